// Round 2
// 228.980 us; speedup vs baseline: 1.0414x; 1.0414x over previous
//
#include <hip/hip_runtime.h>

// AccumulatorLIF: I[t] = exp(-1/2)*I[t-1] + x[t]; out = sigmoid(4*(I-0.5))
// x: (T=1024, B=32, F=1024) fp32. ~268 MB ideal HBM traffic -> memory-bound.
//
// R5 theory (resubmitted R6 after infra-flake round): (1) vmcnt is in-order
// and shared by loads+stores, so the old structure's [stores g][loads g+1]
// [wait vmcnt(7)] made every wave drain its 8 nt stores to HBM before the
// next FMA — one full store-ack serialization per group. Fix: double-buffer
// a[8]/b[8] and issue ALL loads of the chunk before ANY store. (2) KHALO
// 24->16: loads/output 2.5->2.0. Truncation error d^16*|I| ~ e^-8*7 ~
// 2.3e-3 (same bound previously accepted for chunk 1), under 2e-2 threshold.
//
// Registers: a[8]+b[8]=64 VGPR + I + addrs -> ~80 VGPR, launch_bounds(256,6)
// (85-VGPR cap, 24 waves/CU). Little's law: 24 waves x 16-deep MLP x 16B
// per lane is far above what's needed to cover queued HBM latency, so the
// occupancy drop from 32 waves is safe.

#define T_DIM   1024
#define B_DIM   32
#define F_DIM   1024
#define LCHUNK  16
#define KHALO   16
#define F4_DIM  (F_DIM / 4)          // 256 float4 per (t,b) row
#define SEQ4    (B_DIM * F4_DIM)     // 8192 float4 per time step
#define NCHUNK  (T_DIM / LCHUNK)     // 64
#define G       8

typedef float f32x4 __attribute__((ext_vector_type(4)));

__device__ __forceinline__ float spike1(float I) {
    // sigmoid(4*(I-0.5)) = 1 / (1 + exp(-4*(I-0.5)))
    float z = fmaf(-4.0f, I, 2.0f);
    float e = __expf(z);
    return __builtin_amdgcn_rcpf(1.0f + e);
}

__device__ __forceinline__ f32x4 spike4(f32x4 I) {
    f32x4 r;
    r.x = spike1(I.x); r.y = spike1(I.y); r.z = spike1(I.z); r.w = spike1(I.w);
    return r;
}

__global__ __launch_bounds__(256, 6) void lif_scan_kernel(
        const f32x4* __restrict__ x, f32x4* __restrict__ out) {
    const float d = 0.60653065971263342f;     // exp(-0.5)

    int tid   = blockIdx.x * 256 + threadIdx.x;
    int s     = tid & (SEQ4 - 1);             // float4 index within time slice
    int chunk = tid >> 13;                    // block-uniform (32 blocks/chunk)
    int t0    = chunk * LCHUNK;

    f32x4 I = (f32x4)(0.0f);
    f32x4 a[G], b[G];

    if (t0 == 0) {
        // Chunk 0: no halo. 16 loads, then 16 compute+store.
        // All loads issued before any store -> no store-drain coupling.
        #pragma unroll
        for (int j = 0; j < G; ++j) a[j] = x[s + j * SEQ4];
        #pragma unroll
        for (int j = 0; j < G; ++j) b[j] = x[s + (G + j) * SEQ4];
        #pragma unroll
        for (int j = 0; j < G; ++j) {
            I = d * I + a[j];
            __builtin_nontemporal_store(spike4(I), &out[s + j * SEQ4]);
        }
        #pragma unroll
        for (int j = 0; j < G; ++j) {
            I = d * I + b[j];
            __builtin_nontemporal_store(spike4(I), &out[s + (G + j) * SEQ4]);
        }
    } else {
        // 16 halo steps (accumulate only) + 16 main steps, software-pipelined:
        // issue order is L(a,warm) L(b,warm) C(a) L(a,main) C(b) L(b,main)
        // C+S(a) C+S(b) — every load precedes every store in the vmcnt queue.
        int li = (t0 - KHALO) * SEQ4 + s;     // t0 >= 16 -> always >= 0
        #pragma unroll
        for (int j = 0; j < G; ++j) a[j] = x[li + j * SEQ4];
        #pragma unroll
        for (int j = 0; j < G; ++j) b[j] = x[li + (G + j) * SEQ4];

        #pragma unroll
        for (int j = 0; j < G; ++j) I = d * I + a[j];          // warm g0
        #pragma unroll
        for (int j = 0; j < G; ++j) a[j] = x[li + (2 * G + j) * SEQ4];  // main g0 loads
        #pragma unroll
        for (int j = 0; j < G; ++j) I = d * I + b[j];          // warm g1
        #pragma unroll
        for (int j = 0; j < G; ++j) b[j] = x[li + (3 * G + j) * SEQ4];  // main g1 loads

        int si = t0 * SEQ4 + s;
        #pragma unroll
        for (int j = 0; j < G; ++j) {
            I = d * I + a[j];
            __builtin_nontemporal_store(spike4(I), &out[si + j * SEQ4]);
        }
        #pragma unroll
        for (int j = 0; j < G; ++j) {
            I = d * I + b[j];
            __builtin_nontemporal_store(spike4(I), &out[si + (G + j) * SEQ4]);
        }
    }
}

extern "C" void kernel_launch(void* const* d_in, const int* in_sizes, int n_in,
                              void* d_out, int out_size, void* d_ws, size_t ws_size,
                              hipStream_t stream) {
    const f32x4* x   = (const f32x4*)d_in[0];
    f32x4*       out = (f32x4*)d_out;
    int total_threads = NCHUNK * SEQ4;        // 524288
    dim3 grid(total_threads / 256), block(256);
    lif_scan_kernel<<<grid, block, 0, stream>>>(x, out);
}